// Round 10
// baseline (591.468 us; speedup 1.0000x reference)
//
#include <hip/hip_runtime.h>
#include <hip/hip_bf16.h>

typedef __hip_bfloat16 bf16;
typedef unsigned short ushort;

__device__ __forceinline__ float us2f(unsigned int u) {
    union { unsigned int i; float f; } c; c.i = u << 16; return c.f;
}
__device__ __forceinline__ bf16 f2bf(float x) { return __float2bfloat16(x); }
// Output store: clamp (NaN -> -1000) then store as FLOAT32 (ref output dtype).
__device__ __forceinline__ float fcf(float x) {
    return fminf(1000.f, fmaxf(-1000.f, x));
}
__device__ __forceinline__ int iclamp(int v, int lo, int hi) {
    return v < lo ? lo : (v > hi ? hi : v);
}

// B=16, S=512, H=1024, K=32 slots, E=1024, L=2
// inputs: float32 (probe-verified R7; values possibly bf16-rounded by harness)
// out: FLOAT32 (R4 quantitative proof: bf16 -100 pairs read as f32 -100.38; err 100.92 = 100.38+0.54)
// out: cls[32] | node[1024] | edge[32768]
__device__ __forceinline__ int po_ps(const int* po) {
    return ((po[1] | po[3] | po[5]) == 0) ? 2 : 1;   // int64 -> high words 0
}
__device__ __forceinline__ int count_n(const int* po, int b, int ps) {
    int n = 0;
    #pragma unroll
    for (int j = 1; j < 32; ++j) n += (po[(b * 32 + j) * ps] > 0) ? 1 : 0;
    return iclamp(n, 0, 31);
}

__global__ __launch_bounds__(256) void k_sentinel(float* __restrict__ out, int nv, float val) {
    int i = blockIdx.x * 256 + threadIdx.x;
    if (i < nv) out[i] = val;
}

// ---------------- kernel 1: node segment means -> fn (bf16, nb*32 rows) ----------------
__global__ __launch_bounds__(256) void k_nodes(const float* __restrict__ seq,
                                               const int* __restrict__ po,
                                               bf16* __restrict__ fn,
                                               int bbase)
{
    const int b_loc = blockIdx.x >> 5;
    const int k = blockIdx.x & 31;
    const int b = bbase + b_loc;
    const int tid = threadIdx.x;
    const int ps = po_ps(po);
    const int n = count_n(po, b, ps);

    const int h0 = tid * 4;
    float4 acc = make_float4(0.f, 0.f, 0.f, 0.f);
    if (k < n) {
        int s_end   = iclamp(po[(b * 32 + k + 1) * ps], 1, 511);
        int s_begin = (k == 0) ? 1 : iclamp(po[(b * 32 + k) * ps] + 1, 1, 511);
        if (s_end < s_begin) s_end = s_begin;
        const float inv = 1.0f / (float)(s_end - s_begin + 1);
        for (int s = s_begin; s <= s_end; ++s) {
            float4 u = *(const float4*)(seq + ((size_t)(b * 512 + s)) * 1024 + h0);
            acc.x += u.x; acc.y += u.y; acc.z += u.z; acc.w += u.w;
        }
        acc.x *= inv; acc.y *= inv; acc.z *= inv; acc.w *= inv;
    }
    bf16* dst = fn + (size_t)(b_loc * 32 + k) * 1024 + h0;
    dst[0] = f2bf(acc.x); dst[1] = f2bf(acc.y); dst[2] = f2bf(acc.z); dst[3] = f2bf(acc.w);
}

// ---------------- kernel 2: cls head partials + naf row into fn ----------------
// grid (nb, 4 col-chunks of 256)
__global__ __launch_bounds__(256) void k_cls(const float* __restrict__ seq,
                                             const int* __restrict__ po,
                                             const float* __restrict__ nafW, const float* __restrict__ nafb,
                                             const float* __restrict__ clsW, const float* __restrict__ clsb,
                                             const float* __restrict__ clsoW,
                                             bf16* __restrict__ fn,
                                             float* __restrict__ cacc,
                                             int bbase)
{
    const int b_loc = blockIdx.x, q = blockIdx.y, tid = threadIdx.x;
    const int b = bbase + b_loc;
    const int hout = q * 256 + tid;
    __shared__ float xs[1024];
    __shared__ float r0[256], r1[256];
    for (int j = tid; j < 1024; j += 256) xs[j] = seq[(size_t)b * 524288 + j];
    __syncthreads();

    const int ps = po_ps(po);
    const int n = count_n(po, b, ps);

    float ca = 0.f, na = 0.f;
    for (int hin = 0; hin < 1024; ++hin) {
        float x = xs[hin];
        ca = fmaf(x, clsW[(size_t)hin * 1024 + hout], ca);
        na = fmaf(x, nafW[(size_t)hin * 1024 + hout], na);
    }
    fn[(size_t)(b_loc * 32 + n) * 1024 + hout] = f2bf(na + nafb[hout]);

    float h = tanhf(ca + clsb[hout]);
    float2 ow = ((const float2*)clsoW)[hout];
    r0[tid] = h * ow.x; r1[tid] = h * ow.y;
    __syncthreads();
    for (int s = 128; s > 0; s >>= 1) {
        if (tid < s) { r0[tid] += r0[tid + s]; r1[tid] += r1[tid + s]; }
        __syncthreads();
    }
    if (tid == 0) {
        atomicAdd(&cacc[b_loc * 2 + 0], r0[0]);
        atomicAdd(&cacc[b_loc * 2 + 1], r1[0]);
    }
}

// ---------------- kernel 3: fn @ {ndW -> node-head partials, W1+W3 -> U, W2-W3 -> V} ----------------
// grid (nb*2 row-tiles of 16, 2 col-halves of 512, 3 outputs), block 256.
__global__ __launch_bounds__(256) void k_huv(const bf16* __restrict__ X,
                                             const float* __restrict__ ndW, const float* __restrict__ ndb,
                                             const float* __restrict__ noW,
                                             const float* __restrict__ eW,
                                             float* __restrict__ nacc,
                                             bf16* __restrict__ U,
                                             bf16* __restrict__ V)
{
    const int rt = blockIdx.x;
    const int cc = blockIdx.y;
    const int z  = blockIdx.z;

    const int tid = threadIdx.x;
    const int w = tid >> 6, lane = tid & 63;
    const int rg = lane >> 4;
    const int cg = lane & 15;
    const int colb = cc * 512 + w * 128 + cg * 8;
    const int rbase = rt * 16;

    __shared__ float Xs[256 * 16];        // transposed: Xs[kk*16 + r]
    __shared__ float redp[16][2];
    if (tid < 32) redp[tid >> 1][tid & 1] = 0.f;

    const float* W0;
    const float* W1 = nullptr;
    float sgn = 1.f;
    if (z == 0)      { W0 = ndW; }
    else if (z == 1) { W0 = eW; W1 = eW + (size_t)2048 * 1024; }
    else             { W0 = eW + (size_t)1024 * 1024; W1 = eW + (size_t)2048 * 1024; sgn = -1.f; }

    float acc[32];
    #pragma unroll
    for (int i = 0; i < 32; ++i) acc[i] = 0.f;

    const int sr = tid & 15, sq0 = tid >> 4;
    const ushort* Xu = (const ushort*)X;

    for (int ks = 0; ks < 1024; ks += 256) {
        __syncthreads();
        #pragma unroll
        for (int it = 0; it < 4; ++it) {
            int qq = sq0 + it * 16;
            ushort4 xv = *(const ushort4*)(Xu + (size_t)(rbase + sr) * 1024 + ks + qq * 4);
            int kk = qq * 4;
            Xs[(kk + 0) * 16 + sr] = us2f(xv.x);
            Xs[(kk + 1) * 16 + sr] = us2f(xv.y);
            Xs[(kk + 2) * 16 + sr] = us2f(xv.z);
            Xs[(kk + 3) * 16 + sr] = us2f(xv.w);
        }
        __syncthreads();

        for (int kk = 0; kk < 256; ++kk) {
            float4 xv = *(const float4*)&Xs[kk * 16 + rg * 4];
            const float* wp0 = W0 + (size_t)(ks + kk) * 1024 + colb;
            float4 wa = ((const float4*)wp0)[0];
            float4 wb = ((const float4*)wp0)[1];
            float wv[8] = {wa.x, wa.y, wa.z, wa.w, wb.x, wb.y, wb.z, wb.w};
            if (W1) {
                const float* wp1 = W1 + (size_t)(ks + kk) * 1024 + colb;
                float4 va = ((const float4*)wp1)[0];
                float4 vb = ((const float4*)wp1)[1];
                wv[0] = fmaf(sgn, va.x, wv[0]); wv[1] = fmaf(sgn, va.y, wv[1]);
                wv[2] = fmaf(sgn, va.z, wv[2]); wv[3] = fmaf(sgn, va.w, wv[3]);
                wv[4] = fmaf(sgn, vb.x, wv[4]); wv[5] = fmaf(sgn, vb.y, wv[5]);
                wv[6] = fmaf(sgn, vb.z, wv[6]); wv[7] = fmaf(sgn, vb.w, wv[7]);
            }
            #pragma unroll
            for (int jj = 0; jj < 8; ++jj) {
                acc[jj]      = fmaf(xv.x, wv[jj], acc[jj]);
                acc[8 + jj]  = fmaf(xv.y, wv[jj], acc[8 + jj]);
                acc[16 + jj] = fmaf(xv.z, wv[jj], acc[16 + jj]);
                acc[24 + jj] = fmaf(xv.w, wv[jj], acc[24 + jj]);
            }
        }
    }

    const int row0 = rbase + rg * 4;
    if (z == 0) {
        #pragma unroll
        for (int rr = 0; rr < 4; ++rr) {
            float q0 = 0.f, q1 = 0.f;
            #pragma unroll
            for (int jj = 0; jj < 8; ++jj) {
                float t = tanhf(acc[rr * 8 + jj] + ndb[colb + jj]);
                float2 ow = ((const float2*)noW)[colb + jj];
                q0 = fmaf(t, ow.x, q0);
                q1 = fmaf(t, ow.y, q1);
            }
            atomicAdd(&redp[rg * 4 + rr][0], q0);
            atomicAdd(&redp[rg * 4 + rr][1], q1);
        }
        __syncthreads();
        if (tid < 32) {
            const int r = tid >> 1, l = tid & 1;
            atomicAdd(&nacc[(size_t)(rbase + r) * 2 + l], redp[r][l]);
        }
    } else {
        bf16* dstbuf = (z == 1) ? U : V;
        #pragma unroll
        for (int rr = 0; rr < 4; ++rr) {
            bf16* dst = dstbuf + (size_t)(row0 + rr) * 1024 + colb;
            #pragma unroll
            for (int jj = 0; jj < 8; ++jj) dst[jj] = f2bf(acc[rr * 8 + jj]);
        }
    }
}

// ---------------- kernel 4: finalize node + cls logits (FLOAT32 out) ----------------
__global__ __launch_bounds__(256) void k_fin(const float* __restrict__ nacc,
                                             const float* __restrict__ cacc,
                                             const float* __restrict__ nob,
                                             const float* __restrict__ clsob,
                                             float* __restrict__ out,
                                             int bbase, int nb)
{
    const int idx = blockIdx.x * 256 + threadIdx.x;
    const int nn = nb * 64;
    if (idx < nn) {
        out[32 + bbase * 64 + idx] = fcf(nacc[idx] + nob[idx & 1]);
    } else if (idx < nn + nb * 2) {
        const int c = idx - nn;
        out[(bbase + (c >> 1)) * 2 + (c & 1)] = fcf(cacc[c] + clsob[c & 1]);
    }
}

// ---------------- kernel 5: per-edge gather + tanh + H->2 projection (FLOAT32 out) ----------------
__global__ __launch_bounds__(256) void k_edge(const bf16* __restrict__ U,
                                              const bf16* __restrict__ V,
                                              const float* __restrict__ edb,
                                              const float* __restrict__ eoW, const float* __restrict__ eob,
                                              const int* __restrict__ po,
                                              float* __restrict__ out,
                                              int bbase)
{
    const int blk = blockIdx.x;
    const int b_loc = blk >> 8;
    const int b = bbase + b_loc;
    const int tid = threadIdx.x;
    const int w = tid >> 6, lane = tid & 63;
    const int e = (blk & 255) * 4 + w;
    const int ps = po_ps(po);
    const int n = count_n(po, b, ps);
    const int m = n + 1;
    const bool valid = e < m * m;
    int i = 0, j = 0;
    if (valid) { i = e / m; j = e - i * m; }
    i = iclamp(i, 0, 31); j = iclamp(j, 0, 31);

    const ushort* urow = (const ushort*)U + (size_t)(b_loc * 32 + j) * 1024;
    const ushort* vrow = (const ushort*)V + (size_t)(b_loc * 32 + i) * 1024;

    float a0 = 0.f, a1 = 0.f;
    #pragma unroll
    for (int c = 0; c < 16; ++c) {
        const int idx = c * 64 + lane;
        float p = edb[idx];
        if (valid) p += us2f(urow[idx]) + us2f(vrow[idx]);
        float t = tanhf(p);
        float2 ow = ((const float2*)eoW)[idx];
        a0 = fmaf(t, ow.x, a0);
        a1 = fmaf(t, ow.y, a1);
    }
    __shared__ float r0[256], r1[256];
    r0[tid] = a0; r1[tid] = a1;
    __syncthreads();
    for (int s = 32; s > 0; s >>= 1) {
        if (lane < s) { r0[tid] += r0[tid + s]; r1[tid] += r1[tid + s]; }
        __syncthreads();
    }
    if (lane == 0) {
        const size_t o = 32 + 1024 + (size_t)(b * 1024 + e) * 2;
        out[o + 0] = fcf(r0[w * 64] + eob[0]);
        out[o + 1] = fcf(r1[w * 64] + eob[1]);
    }
}

static void run_pass(const float* seq, const int* po,
                     const float* nafW, const float* nafb,
                     const float* clsW, const float* clsb, const float* clsoW, const float* clsob,
                     const float* ndW, const float* ndb, const float* noW, const float* nob,
                     const float* eW, const float* edb, const float* eoW, const float* eob,
                     bf16* fn, bf16* U, bf16* V, float* nacc,
                     float* out, int bbase, int nb, hipStream_t stream)
{
    float* cacc = nacc + nb * 64;
    hipMemsetAsync(nacc, 0, (size_t)nb * 66 * sizeof(float), stream);
    hipLaunchKernelGGL(k_nodes, dim3(nb * 32), dim3(256), 0, stream, seq, po, fn, bbase);
    hipLaunchKernelGGL(k_cls, dim3(nb, 4), dim3(256), 0, stream,
                       seq, po, nafW, nafb, clsW, clsb, clsoW, fn, cacc, bbase);
    hipLaunchKernelGGL(k_huv, dim3(nb * 2, 2, 3), dim3(256), 0, stream,
                       fn, ndW, ndb, noW, eW, nacc, U, V);
    hipLaunchKernelGGL(k_fin, dim3((nb * 66 + 255) / 256), dim3(256), 0, stream,
                       nacc, cacc, nob, clsob, out, bbase, nb);
    hipLaunchKernelGGL(k_edge, dim3(nb * 256), dim3(256), 0, stream,
                       U, V, edb, eoW, eob, po, out, bbase);
}

extern "C" void kernel_launch(void* const* d_in, const int* in_sizes, int n_in,
                              void* d_out, int out_size, void* d_ws, size_t ws_size,
                              hipStream_t stream) {
    (void)out_size;
    float* out = (float*)d_out;

    bool ok = (n_in >= 16)
        && in_sizes[0] == 8388608 && in_sizes[1] == 512
        && in_sizes[2] == 1048576 && in_sizes[3] == 1024
        && in_sizes[4] == 1048576 && in_sizes[5] == 1024
        && in_sizes[6] == 2048    && in_sizes[7] == 2
        && in_sizes[8] == 1048576 && in_sizes[9] == 1024
        && in_sizes[10] == 2048   && in_sizes[11] == 2
        && in_sizes[12] == 3145728 && in_sizes[13] == 1024
        && in_sizes[14] == 2048   && in_sizes[15] == 2;
    if (!ok) {
        hipLaunchKernelGGL(k_sentinel, dim3(133), dim3(256), 0, stream, out, 33824, 111.0f);
        return;
    }

    const float* seq   = (const float*)d_in[0];
    const int*   po    = (const int*)d_in[1];
    const float* nafW  = (const float*)d_in[2];
    const float* nafb  = (const float*)d_in[3];
    const float* clsW  = (const float*)d_in[4];
    const float* clsb  = (const float*)d_in[5];
    const float* clsoW = (const float*)d_in[6];
    const float* clsob = (const float*)d_in[7];
    const float* ndW   = (const float*)d_in[8];
    const float* ndb   = (const float*)d_in[9];
    const float* noW   = (const float*)d_in[10];
    const float* nob   = (const float*)d_in[11];
    const float* eW    = (const float*)d_in[12];
    const float* edb   = (const float*)d_in[13];
    const float* eoW   = (const float*)d_in[14];
    const float* eob   = (const float*)d_in[15];

    char* ws = (char*)d_ws;

    // Tier B: full-batch, bf16 intermediates: fn 1MB | U 1MB | V 1MB | acc 4.2KB
    const size_t fnB = (size_t)512 * 1024 * 2;
    const size_t needB = 3 * fnB + 16 * 66 * sizeof(float);
    // Tier C: per-batch slice: fn 64KB | U 64KB | V 64KB | acc 264B
    const size_t fnC = (size_t)32 * 1024 * 2;
    const size_t needC = 3 * fnC + 66 * sizeof(float);

    if (ws_size >= needB) {
        bf16*  fn   = (bf16*)(ws);
        bf16*  U    = (bf16*)(ws + fnB);
        bf16*  V    = (bf16*)(ws + 2 * fnB);
        float* nacc = (float*)(ws + 3 * fnB);
        run_pass(seq, po, nafW, nafb, clsW, clsb, clsoW, clsob, ndW, ndb, noW, nob,
                 eW, edb, eoW, eob, fn, U, V, nacc, out, 0, 16, stream);
    } else if (ws_size >= needC) {
        bf16*  fn   = (bf16*)(ws);
        bf16*  U    = (bf16*)(ws + fnC);
        bf16*  V    = (bf16*)(ws + 2 * fnC);
        float* nacc = (float*)(ws + 3 * fnC);
        for (int b = 0; b < 16; ++b)
            run_pass(seq, po, nafW, nafb, clsW, clsb, clsoW, clsob, ndW, ndb, noW, nob,
                     eW, edb, eoW, eob, fn, U, V, nacc, out, b, 1, stream);
    } else {
        hipLaunchKernelGGL(k_sentinel, dim3(133), dim3(256), 0, stream, out, 33824, 222.0f);
    }
}

// Round 11
// 317.630 us; speedup vs baseline: 1.8621x; 1.8621x over previous
//
#include <hip/hip_runtime.h>
#include <hip/hip_bf16.h>

typedef __hip_bfloat16 bf16;
typedef unsigned short ushort;

__device__ __forceinline__ float us2f(unsigned int u) {
    union { unsigned int i; float f; } c; c.i = u << 16; return c.f;
}
__device__ __forceinline__ bf16 f2bf(float x) { return __float2bfloat16(x); }
// Output store: clamp (NaN -> -1000); output dtype is FLOAT32 (verified R10 PASS).
__device__ __forceinline__ float fcf(float x) {
    return fminf(1000.f, fmaxf(-1000.f, x));
}
__device__ __forceinline__ int iclamp(int v, int lo, int hi) {
    return v < lo ? lo : (v > hi ? hi : v);
}

// B=16, S=512, H=1024, K=32 slots, E=1024, L=2
// inputs float32; po int32-or-int64 (detected); out float32: cls[32] | node[1024] | edge[32768]
__device__ __forceinline__ int po_ps(const int* po) {
    return ((po[1] | po[3] | po[5]) == 0) ? 2 : 1;
}
__device__ __forceinline__ int count_n(const int* po, int b, int ps) {
    int n = 0;
    #pragma unroll
    for (int j = 1; j < 32; ++j) n += (po[(b * 32 + j) * ps] > 0) ? 1 : 0;
    return iclamp(n, 0, 31);
}

__global__ __launch_bounds__(256) void k_sentinel(float* __restrict__ out, int nv, float val) {
    int i = blockIdx.x * 256 + threadIdx.x;
    if (i < nv) out[i] = val;
}

// ---------------- kernel 1: node segment means -> fn (bf16, nb*32 rows) ----------------
__global__ __launch_bounds__(256) void k_nodes(const float* __restrict__ seq,
                                               const int* __restrict__ po,
                                               bf16* __restrict__ fn,
                                               int bbase)
{
    const int b_loc = blockIdx.x >> 5;
    const int k = blockIdx.x & 31;
    const int b = bbase + b_loc;
    const int tid = threadIdx.x;
    const int ps = po_ps(po);
    const int n = count_n(po, b, ps);

    const int h0 = tid * 4;
    float4 acc = make_float4(0.f, 0.f, 0.f, 0.f);
    if (k < n) {
        int s_end   = iclamp(po[(b * 32 + k + 1) * ps], 1, 511);
        int s_begin = (k == 0) ? 1 : iclamp(po[(b * 32 + k) * ps] + 1, 1, 511);
        if (s_end < s_begin) s_end = s_begin;
        const float inv = 1.0f / (float)(s_end - s_begin + 1);
        for (int s = s_begin; s <= s_end; ++s) {
            float4 u = *(const float4*)(seq + ((size_t)(b * 512 + s)) * 1024 + h0);
            acc.x += u.x; acc.y += u.y; acc.z += u.z; acc.w += u.w;
        }
        acc.x *= inv; acc.y *= inv; acc.z *= inv; acc.w *= inv;
    }
    bf16* dst = fn + (size_t)(b_loc * 32 + k) * 1024 + h0;
    dst[0] = f2bf(acc.x); dst[1] = f2bf(acc.y); dst[2] = f2bf(acc.z); dst[3] = f2bf(acc.w);
}

// ---------------- kernel 2: cls head partials + naf row into fn ----------------
// grid (nb, 4 col-chunks of 256)
__global__ __launch_bounds__(256) void k_cls(const float* __restrict__ seq,
                                             const int* __restrict__ po,
                                             const float* __restrict__ nafW, const float* __restrict__ nafb,
                                             const float* __restrict__ clsW, const float* __restrict__ clsb,
                                             const float* __restrict__ clsoW,
                                             bf16* __restrict__ fn,
                                             float* __restrict__ cacc,
                                             int bbase)
{
    const int b_loc = blockIdx.x, q = blockIdx.y, tid = threadIdx.x;
    const int b = bbase + b_loc;
    const int hout = q * 256 + tid;
    __shared__ float xs[1024];
    __shared__ float r0[256], r1[256];
    for (int j = tid; j < 1024; j += 256) xs[j] = seq[(size_t)b * 524288 + j];
    __syncthreads();

    const int ps = po_ps(po);
    const int n = count_n(po, b, ps);

    float ca = 0.f, na = 0.f;
    for (int hin = 0; hin < 1024; ++hin) {
        float x = xs[hin];
        ca = fmaf(x, clsW[(size_t)hin * 1024 + hout], ca);
        na = fmaf(x, nafW[(size_t)hin * 1024 + hout], na);
    }
    fn[(size_t)(b_loc * 32 + n) * 1024 + hout] = f2bf(na + nafb[hout]);

    float h = tanhf(ca + clsb[hout]);
    float2 ow = ((const float2*)clsoW)[hout];
    r0[tid] = h * ow.x; r1[tid] = h * ow.y;
    __syncthreads();
    for (int s = 128; s > 0; s >>= 1) {
        if (tid < s) { r0[tid] += r0[tid + s]; r1[tid] += r1[tid + s]; }
        __syncthreads();
    }
    if (tid == 0) {
        atomicAdd(&cacc[b_loc * 2 + 0], r0[0]);
        atomicAdd(&cacc[b_loc * 2 + 1], r1[0]);
    }
}

// ---------------- kernel 3: fn @ {ndW -> node-head partials, W1+W3 -> U, W2-W3 -> V} ----------------
// grid (nb*2 row-tiles of 16, 8 col-chunks of 128, 3 outputs), block 256 = 4 waves.
// Waves SPLIT K (4 x 64 per 256-K slab) for occupancy; LDS tree combines partials.
__global__ __launch_bounds__(256) void k_huv(const bf16* __restrict__ X,
                                             const float* __restrict__ ndW, const float* __restrict__ ndb,
                                             const float* __restrict__ noW,
                                             const float* __restrict__ eW,
                                             float* __restrict__ nacc,
                                             bf16* __restrict__ U,
                                             bf16* __restrict__ V)
{
    const int rt = blockIdx.x;            // row tile of 16
    const int cc = blockIdx.y;            // 0..7 (128 cols each)
    const int z  = blockIdx.z;            // 0..2

    const int tid = threadIdx.x;
    const int w = tid >> 6, lane = tid & 63;
    const int rg = lane >> 4;             // 4 rows each
    const int cg = lane & 15;             // 8 cols each
    const int rbase = rt * 16;
    const int colb = cc * 128 + cg * 8;   // global col base for this lane

    __shared__ float LDSb[8192];          // union: Xs (4096 floats) / Rs (8192 floats)
    float* Xs = LDSb;
    float* Rs = LDSb;

    const float* W0;
    const float* W1 = nullptr;
    float sgn = 1.f;
    if (z == 0)      { W0 = ndW; }
    else if (z == 1) { W0 = eW; W1 = eW + (size_t)2048 * 1024; }
    else             { W0 = eW + (size_t)1024 * 1024; W1 = eW + (size_t)2048 * 1024; sgn = -1.f; }

    float acc[32];
    #pragma unroll
    for (int i = 0; i < 32; ++i) acc[i] = 0.f;

    const int sr = tid & 15, sq0 = tid >> 4;
    const ushort* Xu = (const ushort*)X;

    for (int ks = 0; ks < 1024; ks += 256) {
        __syncthreads();
        #pragma unroll
        for (int it = 0; it < 4; ++it) {
            int qq = sq0 + it * 16;
            ushort4 xv = *(const ushort4*)(Xu + (size_t)(rbase + sr) * 1024 + ks + qq * 4);
            int kk = qq * 4;
            Xs[(kk + 0) * 16 + sr] = us2f(xv.x);
            Xs[(kk + 1) * 16 + sr] = us2f(xv.y);
            Xs[(kk + 2) * 16 + sr] = us2f(xv.z);
            Xs[(kk + 3) * 16 + sr] = us2f(xv.w);
        }
        __syncthreads();

        const int k0 = ks + w * 64;       // this wave's K sub-chunk
        if (W1 == nullptr) {
            #pragma unroll 4
            for (int kk = 0; kk < 64; ++kk) {
                float4 xv = *(const float4*)&Xs[(w * 64 + kk) * 16 + rg * 4];
                const float* wp = W0 + (size_t)(k0 + kk) * 1024 + colb;
                float4 wa = ((const float4*)wp)[0];
                float4 wb = ((const float4*)wp)[1];
                acc[0]  = fmaf(xv.x, wa.x, acc[0]);  acc[1]  = fmaf(xv.x, wa.y, acc[1]);
                acc[2]  = fmaf(xv.x, wa.z, acc[2]);  acc[3]  = fmaf(xv.x, wa.w, acc[3]);
                acc[4]  = fmaf(xv.x, wb.x, acc[4]);  acc[5]  = fmaf(xv.x, wb.y, acc[5]);
                acc[6]  = fmaf(xv.x, wb.z, acc[6]);  acc[7]  = fmaf(xv.x, wb.w, acc[7]);
                acc[8]  = fmaf(xv.y, wa.x, acc[8]);  acc[9]  = fmaf(xv.y, wa.y, acc[9]);
                acc[10] = fmaf(xv.y, wa.z, acc[10]); acc[11] = fmaf(xv.y, wa.w, acc[11]);
                acc[12] = fmaf(xv.y, wb.x, acc[12]); acc[13] = fmaf(xv.y, wb.y, acc[13]);
                acc[14] = fmaf(xv.y, wb.z, acc[14]); acc[15] = fmaf(xv.y, wb.w, acc[15]);
                acc[16] = fmaf(xv.z, wa.x, acc[16]); acc[17] = fmaf(xv.z, wa.y, acc[17]);
                acc[18] = fmaf(xv.z, wa.z, acc[18]); acc[19] = fmaf(xv.z, wa.w, acc[19]);
                acc[20] = fmaf(xv.z, wb.x, acc[20]); acc[21] = fmaf(xv.z, wb.y, acc[21]);
                acc[22] = fmaf(xv.z, wb.z, acc[22]); acc[23] = fmaf(xv.z, wb.w, acc[23]);
                acc[24] = fmaf(xv.w, wa.x, acc[24]); acc[25] = fmaf(xv.w, wa.y, acc[25]);
                acc[26] = fmaf(xv.w, wa.z, acc[26]); acc[27] = fmaf(xv.w, wa.w, acc[27]);
                acc[28] = fmaf(xv.w, wb.x, acc[28]); acc[29] = fmaf(xv.w, wb.y, acc[29]);
                acc[30] = fmaf(xv.w, wb.z, acc[30]); acc[31] = fmaf(xv.w, wb.w, acc[31]);
            }
        } else {
            #pragma unroll 4
            for (int kk = 0; kk < 64; ++kk) {
                float4 xv = *(const float4*)&Xs[(w * 64 + kk) * 16 + rg * 4];
                const float* wp0 = W0 + (size_t)(k0 + kk) * 1024 + colb;
                const float* wp1 = W1 + (size_t)(k0 + kk) * 1024 + colb;
                float4 wa = ((const float4*)wp0)[0];
                float4 wb = ((const float4*)wp0)[1];
                float4 va = ((const float4*)wp1)[0];
                float4 vb = ((const float4*)wp1)[1];
                wa.x = fmaf(sgn, va.x, wa.x); wa.y = fmaf(sgn, va.y, wa.y);
                wa.z = fmaf(sgn, va.z, wa.z); wa.w = fmaf(sgn, va.w, wa.w);
                wb.x = fmaf(sgn, vb.x, wb.x); wb.y = fmaf(sgn, vb.y, wb.y);
                wb.z = fmaf(sgn, vb.z, wb.z); wb.w = fmaf(sgn, vb.w, wb.w);
                acc[0]  = fmaf(xv.x, wa.x, acc[0]);  acc[1]  = fmaf(xv.x, wa.y, acc[1]);
                acc[2]  = fmaf(xv.x, wa.z, acc[2]);  acc[3]  = fmaf(xv.x, wa.w, acc[3]);
                acc[4]  = fmaf(xv.x, wb.x, acc[4]);  acc[5]  = fmaf(xv.x, wb.y, acc[5]);
                acc[6]  = fmaf(xv.x, wb.z, acc[6]);  acc[7]  = fmaf(xv.x, wb.w, acc[7]);
                acc[8]  = fmaf(xv.y, wa.x, acc[8]);  acc[9]  = fmaf(xv.y, wa.y, acc[9]);
                acc[10] = fmaf(xv.y, wa.z, acc[10]); acc[11] = fmaf(xv.y, wa.w, acc[11]);
                acc[12] = fmaf(xv.y, wb.x, acc[12]); acc[13] = fmaf(xv.y, wb.y, acc[13]);
                acc[14] = fmaf(xv.y, wb.z, acc[14]); acc[15] = fmaf(xv.y, wb.w, acc[15]);
                acc[16] = fmaf(xv.z, wa.x, acc[16]); acc[17] = fmaf(xv.z, wa.y, acc[17]);
                acc[18] = fmaf(xv.z, wa.z, acc[18]); acc[19] = fmaf(xv.z, wa.w, acc[19]);
                acc[20] = fmaf(xv.z, wb.x, acc[20]); acc[21] = fmaf(xv.z, wb.y, acc[21]);
                acc[22] = fmaf(xv.z, wb.z, acc[22]); acc[23] = fmaf(xv.z, wb.w, acc[23]);
                acc[24] = fmaf(xv.w, wa.x, acc[24]); acc[25] = fmaf(xv.w, wa.y, acc[25]);
                acc[26] = fmaf(xv.w, wa.z, acc[26]); acc[27] = fmaf(xv.w, wa.w, acc[27]);
                acc[28] = fmaf(xv.w, wb.x, acc[28]); acc[29] = fmaf(xv.w, wb.y, acc[29]);
                acc[30] = fmaf(xv.w, wb.z, acc[30]); acc[31] = fmaf(xv.w, wb.w, acc[31]);
            }
        }
    }
    __syncthreads();                      // Xs dead; Rs aliases it

    // dump per-wave partials: Rs[w][row][col], row 0..15, col 0..127
    #pragma unroll
    for (int rr = 0; rr < 4; ++rr) {
        float* dst = &Rs[w * 2048 + (rg * 4 + rr) * 128 + cg * 8];
        *(float4*)(dst)     = make_float4(acc[rr*8+0], acc[rr*8+1], acc[rr*8+2], acc[rr*8+3]);
        *(float4*)(dst + 4) = make_float4(acc[rr*8+4], acc[rr*8+5], acc[rr*8+6], acc[rr*8+7]);
    }
    __syncthreads();

    // thread tid owns row=tid>>4, local cols (tid&15)*8..+7; sum the 4 wave partials
    const int row = tid >> 4;
    const int c0 = (tid & 15) * 8;
    float s[8];
    #pragma unroll
    for (int e = 0; e < 8; ++e) s[e] = 0.f;
    #pragma unroll
    for (int ww = 0; ww < 4; ++ww) {
        const float* src = &Rs[ww * 2048 + row * 128 + c0];
        float4 a = ((const float4*)src)[0];
        float4 b = ((const float4*)src)[1];
        s[0] += a.x; s[1] += a.y; s[2] += a.z; s[3] += a.w;
        s[4] += b.x; s[5] += b.y; s[6] += b.z; s[7] += b.w;
    }

    const int gcol0 = cc * 128 + c0;
    if (z == 0) {
        float q0 = 0.f, q1 = 0.f;
        #pragma unroll
        for (int e = 0; e < 8; ++e) {
            float t = tanhf(s[e] + ndb[gcol0 + e]);
            float2 ow = ((const float2*)noW)[gcol0 + e];
            q0 = fmaf(t, ow.x, q0);
            q1 = fmaf(t, ow.y, q1);
        }
        #pragma unroll
        for (int off = 8; off > 0; off >>= 1) {
            q0 += __shfl_down(q0, off, 16);
            q1 += __shfl_down(q1, off, 16);
        }
        if ((tid & 15) == 0) {
            atomicAdd(&nacc[(size_t)(rbase + row) * 2 + 0], q0);
            atomicAdd(&nacc[(size_t)(rbase + row) * 2 + 1], q1);
        }
    } else {
        bf16* dstbuf = (z == 1) ? U : V;
        bf16* dst = dstbuf + (size_t)(rbase + row) * 1024 + gcol0;
        #pragma unroll
        for (int e = 0; e < 8; ++e) dst[e] = f2bf(s[e]);
    }
}

// ---------------- kernel 4: finalize node + cls logits ----------------
__global__ __launch_bounds__(256) void k_fin(const float* __restrict__ nacc,
                                             const float* __restrict__ cacc,
                                             const float* __restrict__ nob,
                                             const float* __restrict__ clsob,
                                             float* __restrict__ out,
                                             int bbase, int nb)
{
    const int idx = blockIdx.x * 256 + threadIdx.x;
    const int nn = nb * 64;
    if (idx < nn) {
        out[32 + bbase * 64 + idx] = fcf(nacc[idx] + nob[idx & 1]);
    } else if (idx < nn + nb * 2) {
        const int c = idx - nn;
        out[(bbase + (c >> 1)) * 2 + (c & 1)] = fcf(cacc[c] + clsob[c & 1]);
    }
}

// ---------------- kernel 5: per-edge gather + tanh + H->2 projection ----------------
__global__ __launch_bounds__(256) void k_edge(const bf16* __restrict__ U,
                                              const bf16* __restrict__ V,
                                              const float* __restrict__ edb,
                                              const float* __restrict__ eoW, const float* __restrict__ eob,
                                              const int* __restrict__ po,
                                              float* __restrict__ out,
                                              int bbase)
{
    const int blk = blockIdx.x;
    const int b_loc = blk >> 8;
    const int b = bbase + b_loc;
    const int tid = threadIdx.x;
    const int w = tid >> 6, lane = tid & 63;
    const int e = (blk & 255) * 4 + w;
    const int ps = po_ps(po);
    const int n = count_n(po, b, ps);
    const int m = n + 1;
    const bool valid = e < m * m;
    int i = 0, j = 0;
    if (valid) { i = e / m; j = e - i * m; }
    i = iclamp(i, 0, 31); j = iclamp(j, 0, 31);

    const ushort* urow = (const ushort*)U + (size_t)(b_loc * 32 + j) * 1024;
    const ushort* vrow = (const ushort*)V + (size_t)(b_loc * 32 + i) * 1024;

    float a0 = 0.f, a1 = 0.f;
    #pragma unroll
    for (int c = 0; c < 16; ++c) {
        const int idx = c * 64 + lane;
        float p = edb[idx];
        if (valid) p += us2f(urow[idx]) + us2f(vrow[idx]);
        float t = tanhf(p);
        float2 ow = ((const float2*)eoW)[idx];
        a0 = fmaf(t, ow.x, a0);
        a1 = fmaf(t, ow.y, a1);
    }
    __shared__ float r0[256], r1[256];
    r0[tid] = a0; r1[tid] = a1;
    __syncthreads();
    for (int s = 32; s > 0; s >>= 1) {
        if (lane < s) { r0[tid] += r0[tid + s]; r1[tid] += r1[tid + s]; }
        __syncthreads();
    }
    if (lane == 0) {
        const size_t o = 32 + 1024 + (size_t)(b * 1024 + e) * 2;
        out[o + 0] = fcf(r0[w * 64] + eob[0]);
        out[o + 1] = fcf(r1[w * 64] + eob[1]);
    }
}

static void run_pass(const float* seq, const int* po,
                     const float* nafW, const float* nafb,
                     const float* clsW, const float* clsb, const float* clsoW, const float* clsob,
                     const float* ndW, const float* ndb, const float* noW, const float* nob,
                     const float* eW, const float* edb, const float* eoW, const float* eob,
                     bf16* fn, bf16* U, bf16* V, float* nacc,
                     float* out, int bbase, int nb, hipStream_t stream)
{
    float* cacc = nacc + nb * 64;
    hipMemsetAsync(nacc, 0, (size_t)nb * 66 * sizeof(float), stream);
    hipLaunchKernelGGL(k_nodes, dim3(nb * 32), dim3(256), 0, stream, seq, po, fn, bbase);
    hipLaunchKernelGGL(k_cls, dim3(nb, 4), dim3(256), 0, stream,
                       seq, po, nafW, nafb, clsW, clsb, clsoW, fn, cacc, bbase);
    hipLaunchKernelGGL(k_huv, dim3(nb * 2, 8, 3), dim3(256), 0, stream,
                       fn, ndW, ndb, noW, eW, nacc, U, V);
    hipLaunchKernelGGL(k_fin, dim3((nb * 66 + 255) / 256), dim3(256), 0, stream,
                       nacc, cacc, nob, clsob, out, bbase, nb);
    hipLaunchKernelGGL(k_edge, dim3(nb * 256), dim3(256), 0, stream,
                       U, V, edb, eoW, eob, po, out, bbase);
}

extern "C" void kernel_launch(void* const* d_in, const int* in_sizes, int n_in,
                              void* d_out, int out_size, void* d_ws, size_t ws_size,
                              hipStream_t stream) {
    (void)out_size;
    float* out = (float*)d_out;

    bool ok = (n_in >= 16)
        && in_sizes[0] == 8388608 && in_sizes[1] == 512
        && in_sizes[2] == 1048576 && in_sizes[3] == 1024
        && in_sizes[4] == 1048576 && in_sizes[5] == 1024
        && in_sizes[6] == 2048    && in_sizes[7] == 2
        && in_sizes[8] == 1048576 && in_sizes[9] == 1024
        && in_sizes[10] == 2048   && in_sizes[11] == 2
        && in_sizes[12] == 3145728 && in_sizes[13] == 1024
        && in_sizes[14] == 2048   && in_sizes[15] == 2;
    if (!ok) {
        hipLaunchKernelGGL(k_sentinel, dim3(133), dim3(256), 0, stream, out, 33824, 111.0f);
        return;
    }

    const float* seq   = (const float*)d_in[0];
    const int*   po    = (const int*)d_in[1];
    const float* nafW  = (const float*)d_in[2];
    const float* nafb  = (const float*)d_in[3];
    const float* clsW  = (const float*)d_in[4];
    const float* clsb  = (const float*)d_in[5];
    const float* clsoW = (const float*)d_in[6];
    const float* clsob = (const float*)d_in[7];
    const float* ndW   = (const float*)d_in[8];
    const float* ndb   = (const float*)d_in[9];
    const float* noW   = (const float*)d_in[10];
    const float* nob   = (const float*)d_in[11];
    const float* eW    = (const float*)d_in[12];
    const float* edb   = (const float*)d_in[13];
    const float* eoW   = (const float*)d_in[14];
    const float* eob   = (const float*)d_in[15];

    char* ws = (char*)d_ws;

    const size_t fnB = (size_t)512 * 1024 * 2;
    const size_t needB = 3 * fnB + 16 * 66 * sizeof(float);
    const size_t fnC = (size_t)32 * 1024 * 2;
    const size_t needC = 3 * fnC + 66 * sizeof(float);

    if (ws_size >= needB) {
        bf16*  fn   = (bf16*)(ws);
        bf16*  U    = (bf16*)(ws + fnB);
        bf16*  V    = (bf16*)(ws + 2 * fnB);
        float* nacc = (float*)(ws + 3 * fnB);
        run_pass(seq, po, nafW, nafb, clsW, clsb, clsoW, clsob, ndW, ndb, noW, nob,
                 eW, edb, eoW, eob, fn, U, V, nacc, out, 0, 16, stream);
    } else if (ws_size >= needC) {
        bf16*  fn   = (bf16*)(ws);
        bf16*  U    = (bf16*)(ws + fnC);
        bf16*  V    = (bf16*)(ws + 2 * fnC);
        float* nacc = (float*)(ws + 3 * fnC);
        for (int b = 0; b < 16; ++b)
            run_pass(seq, po, nafW, nafb, clsW, clsb, clsoW, clsob, ndW, ndb, noW, nob,
                     eW, edb, eoW, eob, fn, U, V, nacc, out, b, 1, stream);
    } else {
        hipLaunchKernelGGL(k_sentinel, dim3(133), dim3(256), 0, stream, out, 33824, 222.0f);
    }
}

// Round 12
// 212.301 us; speedup vs baseline: 2.7860x; 1.4961x over previous
//
#include <hip/hip_runtime.h>
#include <hip/hip_bf16.h>

typedef __hip_bfloat16 bf16;
typedef unsigned short ushort;
typedef __attribute__((ext_vector_type(8))) short short8v;   // bf16x8 MFMA frag
typedef __attribute__((ext_vector_type(4))) float float4v;   // fp32x4 MFMA acc

__device__ __forceinline__ float us2f(unsigned int u) {
    union { unsigned int i; float f; } c; c.i = u << 16; return c.f;
}
__device__ __forceinline__ bf16 f2bf(float x) { return __float2bfloat16(x); }
__device__ __forceinline__ ushort f2bfu(float x) {
    union { float f; unsigned int i; } c; c.f = x;
    unsigned int lsb = (c.i >> 16) & 1;
    return (ushort)((c.i + 0x7FFF + lsb) >> 16);
}
__device__ __forceinline__ float fcf(float x) {               // out f32, clamp NaN
    return fminf(1000.f, fmaxf(-1000.f, x));
}
__device__ __forceinline__ int iclamp(int v, int lo, int hi) {
    return v < lo ? lo : (v > hi ? hi : v);
}

// B=16, S=512, H=1024, K=32 slots, E=1024, L=2
// inputs f32; po int32-or-int64 (detected); out f32: cls[32] | node[1024] | edge[32768]
__device__ __forceinline__ int po_ps(const int* po) {
    return ((po[1] | po[3] | po[5]) == 0) ? 2 : 1;
}
__device__ __forceinline__ int count_n(const int* po, int b, int ps) {
    int n = 0;
    #pragma unroll
    for (int j = 1; j < 32; ++j) n += (po[(b * 32 + j) * ps] > 0) ? 1 : 0;
    return iclamp(n, 0, 31);
}

__global__ __launch_bounds__(256) void k_sentinel(float* __restrict__ out, int nv, float val) {
    int i = blockIdx.x * 256 + threadIdx.x;
    if (i < nv) out[i] = val;
}

// ---------------- k_prep: Wct[z][n][k] = combined, transposed, bf16 ----------------
// z=0: ndW^T; z=1: (W1+W3)^T; z=2: (W2-W3)^T. 32x32 tiles.
__global__ __launch_bounds__(256) void k_prep(const float* __restrict__ ndW,
                                              const float* __restrict__ eW,
                                              ushort* __restrict__ Wct)
{
    const int kt = blockIdx.x, nt = blockIdx.y, z = blockIdx.z;
    const int tid = threadIdx.x;
    __shared__ float T[32][33];

    const int k_loc = tid >> 3, n0 = (tid & 7) * 4;
    const size_t gofs = (size_t)(kt * 32 + k_loc) * 1024 + nt * 32 + n0;
    float4 v;
    if (z == 0) {
        v = *(const float4*)(ndW + gofs);
    } else if (z == 1) {
        float4 a = *(const float4*)(eW + gofs);
        float4 b = *(const float4*)(eW + (size_t)2048 * 1024 + gofs);
        v = make_float4(a.x + b.x, a.y + b.y, a.z + b.z, a.w + b.w);
    } else {
        float4 a = *(const float4*)(eW + (size_t)1024 * 1024 + gofs);
        float4 b = *(const float4*)(eW + (size_t)2048 * 1024 + gofs);
        v = make_float4(a.x - b.x, a.y - b.y, a.z - b.z, a.w - b.w);
    }
    T[k_loc][n0 + 0] = v.x; T[k_loc][n0 + 1] = v.y;
    T[k_loc][n0 + 2] = v.z; T[k_loc][n0 + 3] = v.w;
    __syncthreads();

    const int n_loc = tid >> 3, k0 = (tid & 7) * 4;
    ushort* dst = Wct + (size_t)z * 1024 * 1024 + (size_t)(nt * 32 + n_loc) * 1024 + kt * 32 + k0;
    ushort4 o;
    o.x = f2bfu(T[k0 + 0][n_loc]); o.y = f2bfu(T[k0 + 1][n_loc]);
    o.z = f2bfu(T[k0 + 2][n_loc]); o.w = f2bfu(T[k0 + 3][n_loc]);
    *(ushort4*)dst = o;
}

// ---------------- k_nodes: segment means -> fn (bf16) ----------------
__global__ __launch_bounds__(256) void k_nodes(const float* __restrict__ seq,
                                               const int* __restrict__ po,
                                               bf16* __restrict__ fn,
                                               int bbase)
{
    const int b_loc = blockIdx.x >> 5;
    const int k = blockIdx.x & 31;
    const int b = bbase + b_loc;
    const int tid = threadIdx.x;
    const int ps = po_ps(po);
    const int n = count_n(po, b, ps);

    const int h0 = tid * 4;
    float4 acc = make_float4(0.f, 0.f, 0.f, 0.f);
    if (k < n) {
        int s_end   = iclamp(po[(b * 32 + k + 1) * ps], 1, 511);
        int s_begin = (k == 0) ? 1 : iclamp(po[(b * 32 + k) * ps] + 1, 1, 511);
        if (s_end < s_begin) s_end = s_begin;
        const float inv = 1.0f / (float)(s_end - s_begin + 1);
        for (int s = s_begin; s <= s_end; ++s) {
            float4 u = *(const float4*)(seq + ((size_t)(b * 512 + s)) * 1024 + h0);
            acc.x += u.x; acc.y += u.y; acc.z += u.z; acc.w += u.w;
        }
        acc.x *= inv; acc.y *= inv; acc.z *= inv; acc.w *= inv;
    }
    bf16* dst = fn + (size_t)(b_loc * 32 + k) * 1024 + h0;
    dst[0] = f2bf(acc.x); dst[1] = f2bf(acc.y); dst[2] = f2bf(acc.z); dst[3] = f2bf(acc.w);
}

// ---------------- k_cls: grid (nb, 16 col-chunks of 64); waves split K ----------------
__global__ __launch_bounds__(256) void k_cls(const float* __restrict__ seq,
                                             const int* __restrict__ po,
                                             const float* __restrict__ nafW, const float* __restrict__ nafb,
                                             const float* __restrict__ clsW, const float* __restrict__ clsb,
                                             const float* __restrict__ clsoW,
                                             bf16* __restrict__ fn,
                                             float* __restrict__ cacc,
                                             int bbase)
{
    const int b_loc = blockIdx.x, q = blockIdx.y, tid = threadIdx.x;
    const int b = bbase + b_loc;
    const int c = tid & 63, kq = tid >> 6;       // wave == K-quarter
    const int hout = q * 64 + c;
    __shared__ float xs[1024];
    __shared__ float red[8][64];
    for (int j = tid; j < 1024; j += 256) xs[j] = seq[(size_t)b * 524288 + j];
    __syncthreads();

    float ca = 0.f, na = 0.f;
    const int kb = kq * 256;
    for (int i = 0; i < 256; ++i) {
        const int k = kb + i;
        float x = xs[k];
        ca = fmaf(x, clsW[(size_t)k * 1024 + hout], ca);
        na = fmaf(x, nafW[(size_t)k * 1024 + hout], na);
    }
    red[kq][c] = ca; red[4 + kq][c] = na;
    __syncthreads();
    if (kq == 0) {
        ca = red[0][c] + red[1][c] + red[2][c] + red[3][c];
        na = red[4][c] + red[5][c] + red[6][c] + red[7][c];
        const int ps = po_ps(po);
        const int n = count_n(po, b, ps);
        fn[(size_t)(b_loc * 32 + n) * 1024 + hout] = f2bf(na + nafb[hout]);
        float h = tanhf(ca + clsb[hout]);
        float2 ow = ((const float2*)clsoW)[hout];
        float q0 = h * ow.x, q1 = h * ow.y;
        #pragma unroll
        for (int off = 32; off > 0; off >>= 1) {
            q0 += __shfl_down(q0, off, 64);
            q1 += __shfl_down(q1, off, 64);
        }
        if (c == 0) {
            atomicAdd(&cacc[b_loc * 2 + 0], q0);
            atomicAdd(&cacc[b_loc * 2 + 1], q1);
        }
    }
}

// ---------------- k_huv_mfma: fn(16 rows) @ Wct[z] via 16x16x32 bf16 MFMA ----------------
// grid (nb*2 rt, 8 cc of 128 cols, 3 z), block 256 = 4 waves; wave w owns 32 cols.
__global__ __launch_bounds__(256) void k_huv_mfma(const bf16* __restrict__ X,
                                                  const ushort* __restrict__ Wct,
                                                  const float* __restrict__ ndb,
                                                  const float* __restrict__ noW,
                                                  float* __restrict__ nacc,
                                                  bf16* __restrict__ U,
                                                  bf16* __restrict__ V)
{
    const int rt = blockIdx.x;
    const int cc = blockIdx.y;
    const int z  = blockIdx.z;
    const int tid = threadIdx.x;
    const int w = tid >> 6, lane = tid & 63;
    const int quad = lane >> 4, l16 = lane & 15;
    const int rbase = rt * 16;

    __shared__ char smem[32768];
    short* A_lds = (short*)smem;          // frag-order A: slot((ks>>5), quad, m) * 8 bf16
    float* Rs    = (float*)smem;          // 16 x 128 f32 epilogue buffer (aliases A)

    // stage A (16 rows x 1024 K) in MFMA fragment order
    {
        const int r = tid >> 4, s = tid & 15;
        const ushort* src = (const ushort*)X + (size_t)(rbase + r) * 1024 + s * 64;
        #pragma unroll
        for (int cch = 0; cch < 8; ++cch) {
            const int k0 = s * 64 + cch * 8;
            uint4 v = *(const uint4*)(src + cch * 8);
            const int slot = ((k0 >> 5) * 64 + ((k0 >> 3) & 3) * 16 + r) * 8;
            *(uint4*)&A_lds[slot] = v;
        }
    }
    __syncthreads();

    const ushort* Wz = Wct + (size_t)z * 1024 * 1024;
    const int nbase = cc * 128 + w * 32;
    const ushort* B0 = Wz + (size_t)(nbase + l16) * 1024 + quad * 8;
    const ushort* B1 = B0 + (size_t)16 * 1024;

    float4v acc0 = {0.f, 0.f, 0.f, 0.f};
    float4v acc1 = {0.f, 0.f, 0.f, 0.f};

    #pragma unroll 4
    for (int ks = 0; ks < 1024; ks += 32) {
        short8v a  = *(const short8v*)&A_lds[((ks >> 5) * 64 + quad * 16 + l16) * 8];
        short8v b0 = *(const short8v*)(B0 + ks);
        short8v b1 = *(const short8v*)(B1 + ks);
        acc0 = __builtin_amdgcn_mfma_f32_16x16x32_bf16(a, b0, acc0, 0, 0, 0);
        acc1 = __builtin_amdgcn_mfma_f32_16x16x32_bf16(a, b1, acc1, 0, 0, 0);
    }
    __syncthreads();                      // A dead; reuse as Rs

    // C/D layout: row = quad*4 + reg, col = l16 (verified m89)
    #pragma unroll
    for (int reg = 0; reg < 4; ++reg) {
        Rs[(quad * 4 + reg) * 128 + w * 32 + l16]      = acc0[reg];
        Rs[(quad * 4 + reg) * 128 + w * 32 + 16 + l16] = acc1[reg];
    }
    __syncthreads();

    const int row = tid >> 4;
    const int c0 = (tid & 15) * 8;
    const int gcol0 = cc * 128 + c0;
    const float* src = &Rs[row * 128 + c0];
    float s[8];
    {
        float4 a = ((const float4*)src)[0];
        float4 b = ((const float4*)src)[1];
        s[0] = a.x; s[1] = a.y; s[2] = a.z; s[3] = a.w;
        s[4] = b.x; s[5] = b.y; s[6] = b.z; s[7] = b.w;
    }
    if (z == 0) {
        float q0 = 0.f, q1 = 0.f;
        #pragma unroll
        for (int e = 0; e < 8; ++e) {
            float t = tanhf(s[e] + ndb[gcol0 + e]);
            float2 ow = ((const float2*)noW)[gcol0 + e];
            q0 = fmaf(t, ow.x, q0);
            q1 = fmaf(t, ow.y, q1);
        }
        #pragma unroll
        for (int off = 8; off > 0; off >>= 1) {
            q0 += __shfl_down(q0, off, 16);
            q1 += __shfl_down(q1, off, 16);
        }
        if ((tid & 15) == 0) {
            atomicAdd(&nacc[(size_t)(rbase + row) * 2 + 0], q0);
            atomicAdd(&nacc[(size_t)(rbase + row) * 2 + 1], q1);
        }
    } else {
        bf16* dstbuf = (z == 1) ? U : V;
        bf16* dst = dstbuf + (size_t)(rbase + row) * 1024 + gcol0;
        #pragma unroll
        for (int e = 0; e < 8; ++e) dst[e] = f2bf(s[e]);
    }
}

// ---------------- k_huv_valu: R11 fallback (ws too small for Wct) ----------------
__global__ __launch_bounds__(256) void k_huv_valu(const bf16* __restrict__ X,
                                                  const float* __restrict__ ndW, const float* __restrict__ ndb,
                                                  const float* __restrict__ noW,
                                                  const float* __restrict__ eW,
                                                  float* __restrict__ nacc,
                                                  bf16* __restrict__ U,
                                                  bf16* __restrict__ V)
{
    const int rt = blockIdx.x, cc = blockIdx.y, z = blockIdx.z;
    const int tid = threadIdx.x;
    const int w = tid >> 6, lane = tid & 63;
    const int rg = lane >> 4, cg = lane & 15;
    const int rbase = rt * 16;
    const int colb = cc * 128 + cg * 8;

    __shared__ float LDSb[8192];
    float* Xs = LDSb;
    float* Rs = LDSb;

    const float* W0;
    const float* W1 = nullptr;
    float sgn = 1.f;
    if (z == 0)      { W0 = ndW; }
    else if (z == 1) { W0 = eW; W1 = eW + (size_t)2048 * 1024; }
    else             { W0 = eW + (size_t)1024 * 1024; W1 = eW + (size_t)2048 * 1024; sgn = -1.f; }

    float acc[32];
    #pragma unroll
    for (int i = 0; i < 32; ++i) acc[i] = 0.f;

    const int sr = tid & 15, sq0 = tid >> 4;
    const ushort* Xu = (const ushort*)X;

    for (int ks = 0; ks < 1024; ks += 256) {
        __syncthreads();
        #pragma unroll
        for (int it = 0; it < 4; ++it) {
            int qq = sq0 + it * 16;
            ushort4 xv = *(const ushort4*)(Xu + (size_t)(rbase + sr) * 1024 + ks + qq * 4);
            int kk = qq * 4;
            Xs[(kk + 0) * 16 + sr] = us2f(xv.x);
            Xs[(kk + 1) * 16 + sr] = us2f(xv.y);
            Xs[(kk + 2) * 16 + sr] = us2f(xv.z);
            Xs[(kk + 3) * 16 + sr] = us2f(xv.w);
        }
        __syncthreads();
        const int k0 = ks + w * 64;
        for (int kk = 0; kk < 64; ++kk) {
            float4 xv = *(const float4*)&Xs[(w * 64 + kk) * 16 + rg * 4];
            const float* wp0 = W0 + (size_t)(k0 + kk) * 1024 + colb;
            float4 wa = ((const float4*)wp0)[0];
            float4 wb = ((const float4*)wp0)[1];
            if (W1) {
                const float* wp1 = W1 + (size_t)(k0 + kk) * 1024 + colb;
                float4 va = ((const float4*)wp1)[0];
                float4 vb = ((const float4*)wp1)[1];
                wa.x = fmaf(sgn, va.x, wa.x); wa.y = fmaf(sgn, va.y, wa.y);
                wa.z = fmaf(sgn, va.z, wa.z); wa.w = fmaf(sgn, va.w, wa.w);
                wb.x = fmaf(sgn, vb.x, wb.x); wb.y = fmaf(sgn, vb.y, wb.y);
                wb.z = fmaf(sgn, vb.z, wb.z); wb.w = fmaf(sgn, vb.w, wb.w);
            }
            float xr[4] = {xv.x, xv.y, xv.z, xv.w};
            #pragma unroll
            for (int rr = 0; rr < 4; ++rr) {
                acc[rr*8+0] = fmaf(xr[rr], wa.x, acc[rr*8+0]);
                acc[rr*8+1] = fmaf(xr[rr], wa.y, acc[rr*8+1]);
                acc[rr*8+2] = fmaf(xr[rr], wa.z, acc[rr*8+2]);
                acc[rr*8+3] = fmaf(xr[rr], wa.w, acc[rr*8+3]);
                acc[rr*8+4] = fmaf(xr[rr], wb.x, acc[rr*8+4]);
                acc[rr*8+5] = fmaf(xr[rr], wb.y, acc[rr*8+5]);
                acc[rr*8+6] = fmaf(xr[rr], wb.z, acc[rr*8+6]);
                acc[rr*8+7] = fmaf(xr[rr], wb.w, acc[rr*8+7]);
            }
        }
    }
    __syncthreads();
    #pragma unroll
    for (int rr = 0; rr < 4; ++rr) {
        float* dst = &Rs[w * 2048 + (rg * 4 + rr) * 128 + cg * 8];
        *(float4*)(dst)     = make_float4(acc[rr*8+0], acc[rr*8+1], acc[rr*8+2], acc[rr*8+3]);
        *(float4*)(dst + 4) = make_float4(acc[rr*8+4], acc[rr*8+5], acc[rr*8+6], acc[rr*8+7]);
    }
    __syncthreads();
    const int row = tid >> 4;
    const int c0 = (tid & 15) * 8;
    float s[8];
    #pragma unroll
    for (int e = 0; e < 8; ++e) s[e] = 0.f;
    #pragma unroll
    for (int ww = 0; ww < 4; ++ww) {
        const float* src = &Rs[ww * 2048 + row * 128 + c0];
        float4 a = ((const float4*)src)[0];
        float4 b = ((const float4*)src)[1];
        s[0] += a.x; s[1] += a.y; s[2] += a.z; s[3] += a.w;
        s[4] += b.x; s[5] += b.y; s[6] += b.z; s[7] += b.w;
    }
    const int gcol0 = cc * 128 + c0;
    if (z == 0) {
        float q0 = 0.f, q1 = 0.f;
        #pragma unroll
        for (int e = 0; e < 8; ++e) {
            float t = tanhf(s[e] + ndb[gcol0 + e]);
            float2 ow = ((const float2*)noW)[gcol0 + e];
            q0 = fmaf(t, ow.x, q0);
            q1 = fmaf(t, ow.y, q1);
        }
        #pragma unroll
        for (int off = 8; off > 0; off >>= 1) {
            q0 += __shfl_down(q0, off, 16);
            q1 += __shfl_down(q1, off, 16);
        }
        if ((tid & 15) == 0) {
            atomicAdd(&nacc[(size_t)(rbase + row) * 2 + 0], q0);
            atomicAdd(&nacc[(size_t)(rbase + row) * 2 + 1], q1);
        }
    } else {
        bf16* dstbuf = (z == 1) ? U : V;
        bf16* dst = dstbuf + (size_t)(rbase + row) * 1024 + gcol0;
        #pragma unroll
        for (int e = 0; e < 8; ++e) dst[e] = f2bf(s[e]);
    }
}

// ---------------- k_fin ----------------
__global__ __launch_bounds__(256) void k_fin(const float* __restrict__ nacc,
                                             const float* __restrict__ cacc,
                                             const float* __restrict__ nob,
                                             const float* __restrict__ clsob,
                                             float* __restrict__ out,
                                             int bbase, int nb)
{
    const int idx = blockIdx.x * 256 + threadIdx.x;
    const int nn = nb * 64;
    if (idx < nn) {
        out[32 + bbase * 64 + idx] = fcf(nacc[idx] + nob[idx & 1]);
    } else if (idx < nn + nb * 2) {
        const int c = idx - nn;
        out[(bbase + (c >> 1)) * 2 + (c & 1)] = fcf(cacc[c] + clsob[c & 1]);
    }
}

// ---------------- k_edge ----------------
__global__ __launch_bounds__(256) void k_edge(const bf16* __restrict__ U,
                                              const bf16* __restrict__ V,
                                              const float* __restrict__ edb,
                                              const float* __restrict__ eoW, const float* __restrict__ eob,
                                              const int* __restrict__ po,
                                              float* __restrict__ out,
                                              int bbase)
{
    const int blk = blockIdx.x;
    const int b_loc = blk >> 8;
    const int b = bbase + b_loc;
    const int tid = threadIdx.x;
    const int w = tid >> 6, lane = tid & 63;
    const int e = (blk & 255) * 4 + w;
    const int ps = po_ps(po);
    const int n = count_n(po, b, ps);
    const int m = n + 1;
    const bool valid = e < m * m;
    int i = 0, j = 0;
    if (valid) { i = e / m; j = e - i * m; }
    i = iclamp(i, 0, 31); j = iclamp(j, 0, 31);

    const ushort* urow = (const ushort*)U + (size_t)(b_loc * 32 + j) * 1024;
    const ushort* vrow = (const ushort*)V + (size_t)(b_loc * 32 + i) * 1024;

    float a0 = 0.f, a1 = 0.f;
    #pragma unroll
    for (int c = 0; c < 16; ++c) {
        const int idx = c * 64 + lane;
        float p = edb[idx];
        if (valid) p += us2f(urow[idx]) + us2f(vrow[idx]);
        float t = tanhf(p);
        float2 ow = ((const float2*)eoW)[idx];
        a0 = fmaf(t, ow.x, a0);
        a1 = fmaf(t, ow.y, a1);
    }
    #pragma unroll
    for (int off = 32; off > 0; off >>= 1) {
        a0 += __shfl_down(a0, off, 64);
        a1 += __shfl_down(a1, off, 64);
    }
    if (lane == 0) {
        const size_t o = 32 + 1024 + (size_t)(b * 1024 + e) * 2;
        out[o + 0] = fcf(a0 + eob[0]);
        out[o + 1] = fcf(a1 + eob[1]);
    }
}

extern "C" void kernel_launch(void* const* d_in, const int* in_sizes, int n_in,
                              void* d_out, int out_size, void* d_ws, size_t ws_size,
                              hipStream_t stream) {
    (void)out_size;
    float* out = (float*)d_out;

    bool ok = (n_in >= 16)
        && in_sizes[0] == 8388608 && in_sizes[1] == 512
        && in_sizes[2] == 1048576 && in_sizes[3] == 1024
        && in_sizes[4] == 1048576 && in_sizes[5] == 1024
        && in_sizes[6] == 2048    && in_sizes[7] == 2
        && in_sizes[8] == 1048576 && in_sizes[9] == 1024
        && in_sizes[10] == 2048   && in_sizes[11] == 2
        && in_sizes[12] == 3145728 && in_sizes[13] == 1024
        && in_sizes[14] == 2048   && in_sizes[15] == 2;
    if (!ok) {
        hipLaunchKernelGGL(k_sentinel, dim3(133), dim3(256), 0, stream, out, 33824, 111.0f);
        return;
    }

    const float* seq   = (const float*)d_in[0];
    const int*   po    = (const int*)d_in[1];
    const float* nafW  = (const float*)d_in[2];
    const float* nafb  = (const float*)d_in[3];
    const float* clsW  = (const float*)d_in[4];
    const float* clsb  = (const float*)d_in[5];
    const float* clsoW = (const float*)d_in[6];
    const float* clsob = (const float*)d_in[7];
    const float* ndW   = (const float*)d_in[8];
    const float* ndb   = (const float*)d_in[9];
    const float* noW   = (const float*)d_in[10];
    const float* nob   = (const float*)d_in[11];
    const float* eW    = (const float*)d_in[12];
    const float* edb   = (const float*)d_in[13];
    const float* eoW   = (const float*)d_in[14];
    const float* eob   = (const float*)d_in[15];

    char* ws = (char*)d_ws;

    const size_t fnB  = (size_t)512 * 1024 * 2;                 // 1 MB per bf16 buffer
    const size_t accB = 8192;
    const size_t wctB = (size_t)3 * 1024 * 1024 * 2;            // 6 MB bf16 Wct
    const size_t needA = 3 * fnB + accB + wctB;                 // ~9.45 MB
    const size_t needB = 3 * fnB + 16 * 66 * sizeof(float);
    const size_t fnC = (size_t)32 * 1024 * 2;
    const size_t needC = 3 * fnC + 66 * sizeof(float);

    if (ws_size >= needA) {
        bf16*   fn   = (bf16*)(ws);
        bf16*   U    = (bf16*)(ws + fnB);
        bf16*   V    = (bf16*)(ws + 2 * fnB);
        float*  nacc = (float*)(ws + 3 * fnB);
        float*  cacc = nacc + 1024;
        ushort* Wct  = (ushort*)(ws + 3 * fnB + accB);
        hipMemsetAsync(nacc, 0, (1024 + 32) * sizeof(float), stream);
        hipLaunchKernelGGL(k_prep, dim3(32, 32, 3), dim3(256), 0, stream, ndW, eW, Wct);
        hipLaunchKernelGGL(k_nodes, dim3(512), dim3(256), 0, stream, seq, po, fn, 0);
        hipLaunchKernelGGL(k_cls, dim3(16, 16), dim3(256), 0, stream,
                           seq, po, nafW, nafb, clsW, clsb, clsoW, fn, cacc, 0);
        hipLaunchKernelGGL(k_huv_mfma, dim3(32, 8, 3), dim3(256), 0, stream,
                           fn, Wct, ndb, noW, nacc, U, V);
        hipLaunchKernelGGL(k_fin, dim3(5), dim3(256), 0, stream, nacc, cacc, nob, clsob, out, 0, 16);
        hipLaunchKernelGGL(k_edge, dim3(4096), dim3(256), 0, stream,
                           U, V, edb, eoW, eob, po, out, 0);
    } else if (ws_size >= needB) {
        bf16*  fn   = (bf16*)(ws);
        bf16*  U    = (bf16*)(ws + fnB);
        bf16*  V    = (bf16*)(ws + 2 * fnB);
        float* nacc = (float*)(ws + 3 * fnB);
        float* cacc = nacc + 1024;
        hipMemsetAsync(nacc, 0, (1024 + 32) * sizeof(float), stream);
        hipLaunchKernelGGL(k_nodes, dim3(512), dim3(256), 0, stream, seq, po, fn, 0);
        hipLaunchKernelGGL(k_cls, dim3(16, 16), dim3(256), 0, stream,
                           seq, po, nafW, nafb, clsW, clsb, clsoW, fn, cacc, 0);
        hipLaunchKernelGGL(k_huv_valu, dim3(32, 8, 3), dim3(256), 0, stream,
                           fn, ndW, ndb, noW, eW, nacc, U, V);
        hipLaunchKernelGGL(k_fin, dim3(5), dim3(256), 0, stream, nacc, cacc, nob, clsob, out, 0, 16);
        hipLaunchKernelGGL(k_edge, dim3(4096), dim3(256), 0, stream,
                           U, V, edb, eoW, eob, po, out, 0);
    } else if (ws_size >= needC) {
        bf16*  fn   = (bf16*)(ws);
        bf16*  U    = (bf16*)(ws + fnC);
        bf16*  V    = (bf16*)(ws + 2 * fnC);
        float* nacc = (float*)(ws + 3 * fnC);
        float* cacc = nacc + 64;
        for (int b = 0; b < 16; ++b) {
            hipMemsetAsync(nacc, 0, 66 * sizeof(float), stream);
            hipLaunchKernelGGL(k_nodes, dim3(32), dim3(256), 0, stream, seq, po, fn, b);
            hipLaunchKernelGGL(k_cls, dim3(1, 16), dim3(256), 0, stream,
                               seq, po, nafW, nafb, clsW, clsb, clsoW, fn, cacc, b);
            hipLaunchKernelGGL(k_huv_valu, dim3(2, 8, 3), dim3(256), 0, stream,
                               fn, ndW, ndb, noW, eW, nacc, U, V);
            hipLaunchKernelGGL(k_fin, dim3(1), dim3(256), 0, stream, nacc, cacc, nob, clsob, out, b, 1);
            hipLaunchKernelGGL(k_edge, dim3(256), dim3(256), 0, stream,
                               U, V, edb, eoW, eob, po, out, b);
        }
    } else {
        hipLaunchKernelGGL(k_sentinel, dim3(133), dim3(256), 0, stream, out, 33824, 222.0f);
    }
}